// Round 1
// baseline (487.182 us; speedup 1.0000x reference)
//
#include <hip/hip_runtime.h>
#include <math.h>

#define N_NODES 50000
#define E_RAW   400000
#define E_TOT   (E_RAW + N_NODES)   // 450000 incl. self loops
#define NEG_SLOPE 0.2f

__device__ __forceinline__ void fma4(float4& a, float s, const float4& w) {
    a.x += s * w.x; a.y += s * w.y; a.z += s * w.z; a.w += s * w.w;
}
__device__ __forceinline__ float dot4(const float4& a, const float4& b) {
    return a.x*b.x + a.y*b.y + a.z*b.z + a.w*b.w;
}

// ---------------- CSR build ----------------

__global__ void k_hist(const int* __restrict__ ei, int* __restrict__ cnt) {
    int e = blockIdx.x * 256 + threadIdx.x;
    if (e >= E_TOT) return;
    int dst = (e < E_RAW) ? ei[E_RAW + e] : (e - E_RAW);
    atomicAdd(&cnt[dst], 1);
}

__global__ void k_scan1(const int* __restrict__ cnt, int* __restrict__ offs,
                        int* __restrict__ bsum) {
    __shared__ int s[256];
    int i = blockIdx.x * 256 + threadIdx.x;
    int v = (i < N_NODES) ? cnt[i] : 0;
    s[threadIdx.x] = v;
    __syncthreads();
    for (int d = 1; d < 256; d <<= 1) {
        int t = (threadIdx.x >= d) ? s[threadIdx.x - d] : 0;
        __syncthreads();
        s[threadIdx.x] += t;
        __syncthreads();
    }
    if (i < N_NODES) offs[i] = s[threadIdx.x] - v;   // exclusive
    if (threadIdx.x == 255) bsum[blockIdx.x] = s[255];
}

__global__ void k_scan2(int* __restrict__ bsum, int nb) {
    __shared__ int s[256];
    int v = (threadIdx.x < nb) ? bsum[threadIdx.x] : 0;
    s[threadIdx.x] = v;
    __syncthreads();
    for (int d = 1; d < 256; d <<= 1) {
        int t = (threadIdx.x >= d) ? s[threadIdx.x - d] : 0;
        __syncthreads();
        s[threadIdx.x] += t;
        __syncthreads();
    }
    if (threadIdx.x < nb) bsum[threadIdx.x] = s[threadIdx.x] - v;  // exclusive
}

__global__ void k_scan3(int* __restrict__ offs, const int* __restrict__ bsum) {
    int i = blockIdx.x * 256 + threadIdx.x;
    if (i < N_NODES) offs[i] += bsum[blockIdx.x];
}

__global__ void k_scatter(const int* __restrict__ ei, const int* __restrict__ offs,
                          int* __restrict__ cursor, int* __restrict__ srcs) {
    int e = blockIdx.x * 256 + threadIdx.x;
    if (e >= E_TOT) return;
    int src, dst;
    if (e < E_RAW) { src = ei[e]; dst = ei[E_RAW + e]; }
    else           { src = dst = e - E_RAW; }
    int pos = offs[dst] + atomicAdd(&cursor[dst], 1);
    srcs[pos] = src;
}

// ---------------- GEMM 256-out, fused alpha dots ----------------
// block = 256 thr = 4 waves; block computes 16 rows x 256 cols.
// wave w owns rows w*4..w*4+3; lane owns cols lane*4..lane*4+3.

__global__ __launch_bounds__(256) void k_gemm256(
        const float* __restrict__ X, const float* __restrict__ W,
        const float* __restrict__ a_s, const float* __restrict__ a_d,
        float* __restrict__ H, float* __restrict__ As, float* __restrict__ Ad) {
    __shared__ float xs[16][32];
    __shared__ float ws[32][256];
    const int tid  = threadIdx.x;
    const int lane = tid & 63;
    const int wv   = tid >> 6;
    const int c0   = lane * 4;
    const int rowg = blockIdx.x * 16;

    float4 acc[4] = {};

    for (int k0 = 0; k0 < 256; k0 += 32) {
        // stage x tile: 16x32 = 512 elems, 2 per thread
        {
            int e = tid;
            #pragma unroll
            for (int i = 0; i < 2; ++i) {
                int r = e >> 5, kk = e & 31;
                xs[r][kk] = X[(rowg + r) * 256 + k0 + kk];
                e += 256;
            }
        }
        // stage W tile: 32x256 = 2048 float4, 8 per thread
        {
            #pragma unroll
            for (int i = 0; i < 8; ++i) {
                int f = tid + i * 256;
                int kk = f >> 6, cc = (f & 63) * 4;
                *(float4*)&ws[kk][cc] = *(const float4*)&W[(k0 + kk) * 256 + cc];
            }
        }
        __syncthreads();
        #pragma unroll
        for (int kk = 0; kk < 32; kk += 4) {
            float4 xv[4], wvv[4];
            #pragma unroll
            for (int r = 0; r < 4; ++r) xv[r] = *(const float4*)&xs[wv * 4 + r][kk];
            #pragma unroll
            for (int i = 0; i < 4; ++i) wvv[i] = *(const float4*)&ws[kk + i][c0];
            #pragma unroll
            for (int r = 0; r < 4; ++r) {
                fma4(acc[r], xv[r].x, wvv[0]);
                fma4(acc[r], xv[r].y, wvv[1]);
                fma4(acc[r], xv[r].z, wvv[2]);
                fma4(acc[r], xv[r].w, wvv[3]);
            }
        }
        __syncthreads();
    }

    const float4 asv = *(const float4*)&a_s[c0];
    const float4 adv = *(const float4*)&a_d[c0];
    #pragma unroll
    for (int r = 0; r < 4; ++r) {
        int row = rowg + wv * 4 + r;
        *(float4*)&H[row * 256 + c0] = acc[r];
        float ss = dot4(acc[r], asv);
        float sd = dot4(acc[r], adv);
        #pragma unroll
        for (int o = 32; o; o >>= 1) {
            ss += __shfl_xor(ss, o);
            sd += __shfl_xor(sd, o);
        }
        if (lane == 0) { As[row] = ss; Ad[row] = sd; }
    }
}

// ---------------- GEMM 32-out (layer 2), fused alpha dots ----------------
// block = 256 thr; 32 rows/block; thread (rl, cg): rl = tid/8 row, cg = (tid&7)*4 cols.

__global__ __launch_bounds__(256) void k_gemm32(
        const float* __restrict__ X, const float* __restrict__ W,  // W: [256][32]
        const float* __restrict__ a_s, const float* __restrict__ a_d,
        float* __restrict__ H, float* __restrict__ As, float* __restrict__ Ad) {
    __shared__ float ws[256][32];
    __shared__ float xs[32][36];   // +4 pad: break 8-way bank conflict
    const int tid = threadIdx.x;
    // stage whole W2 (32KB)
    #pragma unroll
    for (int i = 0; i < 8; ++i) {
        int f = tid + i * 256;
        int r = f >> 3, cc = (f & 7) * 4;
        *(float4*)&ws[r][cc] = *(const float4*)&W[r * 32 + cc];
    }
    const int rl = tid >> 3;
    const int cg = (tid & 7) * 4;
    const int rowg = blockIdx.x * 32;
    const int row = rowg + rl;
    const bool valid = row < N_NODES;
    float4 acc = {};
    __syncthreads();

    for (int k0 = 0; k0 < 256; k0 += 32) {
        {   // stage x tile 32x32: 256 float4, 1 per thread
            int r = tid >> 3, kk = (tid & 7) * 4;
            int gr = rowg + r;
            float4 v = {0, 0, 0, 0};
            if (gr < N_NODES) v = *(const float4*)&X[gr * 256 + k0 + kk];
            *(float4*)&xs[r][kk] = v;
        }
        __syncthreads();
        #pragma unroll
        for (int kk = 0; kk < 32; kk += 4) {
            float4 xv = *(const float4*)&xs[rl][kk];
            fma4(acc, xv.x, *(const float4*)&ws[k0 + kk + 0][cg]);
            fma4(acc, xv.y, *(const float4*)&ws[k0 + kk + 1][cg]);
            fma4(acc, xv.z, *(const float4*)&ws[k0 + kk + 2][cg]);
            fma4(acc, xv.w, *(const float4*)&ws[k0 + kk + 3][cg]);
        }
        __syncthreads();
    }

    float ss = dot4(acc, *(const float4*)&a_s[cg]);
    float sd = dot4(acc, *(const float4*)&a_d[cg]);
    #pragma unroll
    for (int o = 4; o; o >>= 1) {   // reduce over the 8-thread row group
        ss += __shfl_xor(ss, o);
        sd += __shfl_xor(sd, o);
    }
    if (valid) {
        *(float4*)&H[row * 32 + cg] = acc;
        if ((tid & 7) == 0) { As[row] = ss; Ad[row] = sd; }
    }
}

// ---------------- Aggregation (256-wide), fused bias + swish ----------------
// 1 wave per dst node; lane owns cols lane*4..+3.

template<bool SWISH>
__global__ __launch_bounds__(256) void k_agg256(
        const float* __restrict__ H, const float* __restrict__ As,
        const float* __restrict__ Ad,
        const int* __restrict__ offs, const int* __restrict__ cnts,
        const int* __restrict__ srcs,
        const float* __restrict__ bias, float* __restrict__ Hout) {
    const int lane = threadIdx.x & 63;
    const int node = blockIdx.x * 4 + (threadIdx.x >> 6);
    if (node >= N_NODES) return;
    const int start = offs[node];
    const int cnt   = cnts[node];
    const float ad  = Ad[node];

    float m = -1e30f;
    for (int base = 0; base < cnt; base += 64) {
        int i = base + lane;
        if (i < cnt) {
            int s = srcs[start + i];
            float e = As[s] + ad;
            e = e > 0.f ? e : NEG_SLOPE * e;
            m = fmaxf(m, e);
        }
    }
    #pragma unroll
    for (int o = 32; o; o >>= 1) m = fmaxf(m, __shfl_xor(m, o));

    float4 acc = {0.f, 0.f, 0.f, 0.f};
    float denom = 0.f;
    const int c0 = lane * 4;
    for (int base = 0; base < cnt; base += 64) {
        int i = base + lane;
        int s = 0; float p = 0.f;
        if (i < cnt) {
            s = srcs[start + i];
            float e = As[s] + ad;
            e = e > 0.f ? e : NEG_SLOPE * e;
            p = __expf(e - m);
            denom += p;
        }
        int lim = min(64, cnt - base);
        for (int j = 0; j < lim; ++j) {
            float pj = __shfl(p, j);
            int   sj = __shfl(s, j);
            const float4 hv = *(const float4*)&H[sj * 256 + c0];
            fma4(acc, pj, hv);
        }
    }
    #pragma unroll
    for (int o = 32; o; o >>= 1) denom += __shfl_xor(denom, o);
    const float inv = 1.f / denom;
    const float4 bv = *(const float4*)&bias[c0];
    float4 o4;
    o4.x = acc.x * inv + bv.x;
    o4.y = acc.y * inv + bv.y;
    o4.z = acc.z * inv + bv.z;
    o4.w = acc.w * inv + bv.w;
    if (SWISH) {
        o4.x = o4.x / (1.f + __expf(-o4.x));
        o4.y = o4.y / (1.f + __expf(-o4.y));
        o4.z = o4.z / (1.f + __expf(-o4.z));
        o4.w = o4.w / (1.f + __expf(-o4.w));
    }
    *(float4*)&Hout[node * 256 + c0] = o4;
}

// ---------------- Final aggregation (32-wide) + bias + log_softmax ----------------

__global__ __launch_bounds__(256) void k_agg_final(
        const float* __restrict__ H,   // [N][32]
        const float* __restrict__ As, const float* __restrict__ Ad,
        const int* __restrict__ offs, const int* __restrict__ cnts,
        const int* __restrict__ srcs,
        const float* __restrict__ bias, float* __restrict__ out) {
    const int lane = threadIdx.x & 63;
    const int node = blockIdx.x * 4 + (threadIdx.x >> 6);
    if (node >= N_NODES) return;
    const int start = offs[node];
    const int cnt   = cnts[node];
    const float ad  = Ad[node];

    float m = -1e30f;
    for (int base = 0; base < cnt; base += 64) {
        int i = base + lane;
        if (i < cnt) {
            int s = srcs[start + i];
            float e = As[s] + ad;
            e = e > 0.f ? e : NEG_SLOPE * e;
            m = fmaxf(m, e);
        }
    }
    #pragma unroll
    for (int o = 32; o; o >>= 1) m = fmaxf(m, __shfl_xor(m, o));

    float acc = 0.f, denom = 0.f;
    const int c = lane & 31;
    for (int base = 0; base < cnt; base += 64) {
        int i = base + lane;
        int s = 0; float p = 0.f;
        if (i < cnt) {
            s = srcs[start + i];
            float e = As[s] + ad;
            e = e > 0.f ? e : NEG_SLOPE * e;
            p = __expf(e - m);
            denom += p;
        }
        int lim = min(64, cnt - base);
        for (int j = 0; j < lim; ++j) {
            float pj = __shfl(p, j);
            int   sj = __shfl(s, j);
            acc += pj * H[sj * 32 + c];
        }
    }
    #pragma unroll
    for (int o = 32; o; o >>= 1) denom += __shfl_xor(denom, o);

    float v = acc / denom + bias[c];
    // log_softmax across the 32 classes (both half-waves hold duplicates)
    float mm = v;
    #pragma unroll
    for (int o = 16; o; o >>= 1) mm = fmaxf(mm, __shfl_xor(mm, o));
    float ex = __expf(v - mm), sum = ex;
    #pragma unroll
    for (int o = 16; o; o >>= 1) sum += __shfl_xor(sum, o);
    float r = v - mm - __logf(sum);
    if (lane < 32) out[node * 32 + c] = r;
}

// ---------------- launch ----------------

extern "C" void kernel_launch(void* const* d_in, const int* in_sizes, int n_in,
                              void* d_out, int out_size, void* d_ws, size_t ws_size,
                              hipStream_t stream) {
    const float* x   = (const float*)d_in[0];
    const int*   ei  = (const int*)  d_in[1];
    const float* W0  = (const float*)d_in[2];
    const float* as0 = (const float*)d_in[3];
    const float* ad0 = (const float*)d_in[4];
    const float* b0  = (const float*)d_in[5];
    const float* W1  = (const float*)d_in[6];
    const float* as1 = (const float*)d_in[7];
    const float* ad1 = (const float*)d_in[8];
    const float* b1  = (const float*)d_in[9];
    const float* W2  = (const float*)d_in[10];
    const float* as2 = (const float*)d_in[11];
    const float* ad2 = (const float*)d_in[12];
    const float* b2  = (const float*)d_in[13];
    float* out = (float*)d_out;

    char* ws = (char*)d_ws;
    float* hA    = (float*)(ws + 0);            // 51,200,000 B
    float* hB    = (float*)(ws + 51200000);     // 51,200,000 B
    float* As    = (float*)(ws + 102400000);    // 200,000 B
    float* Ad    = (float*)(ws + 102600000);    // 200,000 B
    int*   cnts  = (int*)  (ws + 102800000);    // 200,000 B
    int*   offs  = (int*)  (ws + 103000000);    // 200,000 B
    int*   cursor= (int*)  (ws + 103200000);    // 200,000 B
    int*   srcs  = (int*)  (ws + 103400000);    // 1,800,000 B
    int*   bsum  = (int*)  (ws + 105200000);    // 1,024 B

    const int NB = (N_NODES + 255) / 256;       // 196

    hipMemsetAsync(cnts,   0, N_NODES * sizeof(int), stream);
    hipMemsetAsync(cursor, 0, N_NODES * sizeof(int), stream);

    k_hist   <<<(E_TOT + 255) / 256, 256, 0, stream>>>(ei, cnts);
    k_scan1  <<<NB, 256, 0, stream>>>(cnts, offs, bsum);
    k_scan2  <<<1, 256, 0, stream>>>(bsum, NB);
    k_scan3  <<<NB, 256, 0, stream>>>(offs, bsum);
    k_scatter<<<(E_TOT + 255) / 256, 256, 0, stream>>>(ei, offs, cursor, srcs);

    const int AGG_BLOCKS = (N_NODES + 3) / 4;   // 12500

    // layer 0
    k_gemm256<<<N_NODES / 16, 256, 0, stream>>>(x, W0, as0, ad0, hA, As, Ad);
    k_agg256<true><<<AGG_BLOCKS, 256, 0, stream>>>(hA, As, Ad, offs, cnts, srcs, b0, hB);
    // layer 1
    k_gemm256<<<N_NODES / 16, 256, 0, stream>>>(hB, W1, as1, ad1, hA, As, Ad);
    k_agg256<true><<<AGG_BLOCKS, 256, 0, stream>>>(hA, As, Ad, offs, cnts, srcs, b1, hB);
    // layer 2 (+ fused log_softmax)
    k_gemm32<<<(N_NODES + 31) / 32, 256, 0, stream>>>(hB, W2, as2, ad2, hA, As, Ad);
    k_agg_final<<<AGG_BLOCKS, 256, 0, stream>>>(hA, As, Ad, offs, cnts, srcs, b2, out);
}

// Round 2
// 381.257 us; speedup vs baseline: 1.2778x; 1.2778x over previous
//
#include <hip/hip_runtime.h>
#include <math.h>

#define N_NODES 50000
#define E_RAW   400000
#define E_TOT   (E_RAW + N_NODES)   // 450000 incl. self loops
#define NEG_SLOPE 0.2f

typedef __bf16 bf16_t;
typedef bf16_t bf16x8 __attribute__((ext_vector_type(8)));
typedef float  f32x4  __attribute__((ext_vector_type(4)));

// LDS bank-group swizzle (applied identically on write and read)
#define SWZ(r) (((r) ^ ((r) >> 3)) & 7)

__device__ __forceinline__ void fma4(float4& a, float s, const float4& w) {
    a.x += s * w.x; a.y += s * w.y; a.z += s * w.z; a.w += s * w.w;
}
__device__ __forceinline__ float dot4(const float4& a, const float4& b) {
    return a.x*b.x + a.y*b.y + a.z*b.z + a.w*b.w;
}

// ---------------- CSR build ----------------

__global__ void k_hist(const int* __restrict__ ei, int* __restrict__ cnt) {
    int e = blockIdx.x * 256 + threadIdx.x;
    if (e >= E_TOT) return;
    int dst = (e < E_RAW) ? ei[E_RAW + e] : (e - E_RAW);
    atomicAdd(&cnt[dst], 1);
}

__global__ void k_scan1(const int* __restrict__ cnt, int* __restrict__ offs,
                        int* __restrict__ bsum) {
    __shared__ int s[256];
    int i = blockIdx.x * 256 + threadIdx.x;
    int v = (i < N_NODES) ? cnt[i] : 0;
    s[threadIdx.x] = v;
    __syncthreads();
    for (int d = 1; d < 256; d <<= 1) {
        int t = (threadIdx.x >= d) ? s[threadIdx.x - d] : 0;
        __syncthreads();
        s[threadIdx.x] += t;
        __syncthreads();
    }
    if (i < N_NODES) offs[i] = s[threadIdx.x] - v;   // exclusive
    if (threadIdx.x == 255) bsum[blockIdx.x] = s[255];
}

__global__ void k_scan2(int* __restrict__ bsum, int nb) {
    __shared__ int s[256];
    int v = (threadIdx.x < nb) ? bsum[threadIdx.x] : 0;
    s[threadIdx.x] = v;
    __syncthreads();
    for (int d = 1; d < 256; d <<= 1) {
        int t = (threadIdx.x >= d) ? s[threadIdx.x - d] : 0;
        __syncthreads();
        s[threadIdx.x] += t;
        __syncthreads();
    }
    if (threadIdx.x < nb) bsum[threadIdx.x] = s[threadIdx.x] - v;  // exclusive
}

__global__ void k_scan3(int* __restrict__ offs, const int* __restrict__ bsum) {
    int i = blockIdx.x * 256 + threadIdx.x;
    if (i < N_NODES) offs[i] += bsum[blockIdx.x];
}

__global__ void k_scatter(const int* __restrict__ ei, const int* __restrict__ offs,
                          int* __restrict__ cursor, int* __restrict__ srcs) {
    int e = blockIdx.x * 256 + threadIdx.x;
    if (e >= E_TOT) return;
    int src, dst;
    if (e < E_RAW) { src = ei[e]; dst = ei[E_RAW + e]; }
    else           { src = dst = e - E_RAW; }
    int pos = offs[dst] + atomicAdd(&cursor[dst], 1);
    srcs[pos] = src;
}

// ---------------- W transpose + bf16 hi/lo split ----------------
// W: [256][256] (k-major rows) -> Wt_hi/Wt_lo: [n][k] bf16

__global__ void k_split_w(const float* __restrict__ W,
                          bf16_t* __restrict__ Wth, bf16_t* __restrict__ Wtl) {
    int idx = blockIdx.x * 256 + threadIdx.x;   // 65536 total
    int k = idx >> 8, n = idx & 255;
    float v = W[k * 256 + n];
    bf16_t h = (bf16_t)v;
    Wth[n * 256 + k] = h;
    Wtl[n * 256 + k] = (bf16_t)(v - (float)h);
}

// ---------------- MFMA GEMM (bf16x3 split), fused alpha dots ----------------
// BM=64 rows/block, BN=256 (full), BK=32. 4 waves; wave w owns cols w*64..+63
// as a 4x4 grid of 16x16 fragments. 3 mfma per fragment pair (hi*hi+hi*lo+lo*hi).

#define BM 64
#define BK 32

__global__ __launch_bounds__(256) void k_gemm256_mfma(
        const float* __restrict__ X,
        const bf16_t* __restrict__ Bth, const bf16_t* __restrict__ Btl,
        const float* __restrict__ a_s, const float* __restrict__ a_d,
        float* __restrict__ H, float* __restrict__ As, float* __restrict__ Ad) {
    __shared__ __align__(16) bf16_t AhS[BM * BK];
    __shared__ __align__(16) bf16_t AlS[BM * BK];
    __shared__ __align__(16) bf16_t BhS[256 * BK];
    __shared__ __align__(16) bf16_t BlS[256 * BK];

    const int tid  = threadIdx.x;
    const int lane = tid & 63;
    const int wv   = tid >> 6;          // 0..3: col block wv*64
    const int rowg = blockIdx.x * BM;

    f32x4 acc[4][4] = {};

    // A staging coords: thread -> (row ar, k-sub ak), 8 floats
    const int ar = tid >> 2;
    const int ak = (tid & 3) * 8;
    const int arow_g = min(rowg + ar, N_NODES - 1);   // clamp (garbage rows discarded)
    const int ae = ((ar * BK + ak) ^ (SWZ(ar) << 3));
    // B staging coords: thread stages row n = tid (32 k = 4 x b128), hi+lo
    const int bbase = tid * BK;
    const int bx = SWZ(tid) << 3;

    // fragment read coords
    const int r16  = lane & 15;
    const int koff = (lane >> 4) * 8;

    for (int k0 = 0; k0 < 256; k0 += BK) {
        // ---- stage A (fp32 -> hi/lo bf16) ----
        float4 v0 = *(const float4*)&X[arow_g * 256 + k0 + ak];
        float4 v1 = *(const float4*)&X[arow_g * 256 + k0 + ak + 4];
        float xv8[8] = {v0.x, v0.y, v0.z, v0.w, v1.x, v1.y, v1.z, v1.w};
        bf16x8 hi, lo;
        #pragma unroll
        for (int i = 0; i < 8; ++i) {
            bf16_t h = (bf16_t)xv8[i];
            hi[i] = h;
            lo[i] = (bf16_t)(xv8[i] - (float)h);
        }
        *(bf16x8*)&AhS[ae] = hi;
        *(bf16x8*)&AlS[ae] = lo;
        // ---- stage B (pre-split bf16) ----
        const bf16x8* gh = (const bf16x8*)&Bth[tid * 256 + k0];
        const bf16x8* gl = (const bf16x8*)&Btl[tid * 256 + k0];
        #pragma unroll
        for (int j = 0; j < 4; ++j) {
            *(bf16x8*)&BhS[(bbase + j * 8) ^ bx] = gh[j];
            *(bf16x8*)&BlS[(bbase + j * 8) ^ bx] = gl[j];
        }
        __syncthreads();

        // ---- fragments ----
        bf16x8 ah[4], al[4], bh[4], bl[4];
        #pragma unroll
        for (int m = 0; m < 4; ++m) {
            int row = m * 16 + r16;
            int e = ((row * BK + koff) ^ (SWZ(row) << 3));
            ah[m] = *(const bf16x8*)&AhS[e];
            al[m] = *(const bf16x8*)&AlS[e];
        }
        #pragma unroll
        for (int n = 0; n < 4; ++n) {
            int col = wv * 64 + n * 16 + r16;
            int e = ((col * BK + koff) ^ (SWZ(col) << 3));
            bh[n] = *(const bf16x8*)&BhS[e];
            bl[n] = *(const bf16x8*)&BlS[e];
        }
        #pragma unroll
        for (int m = 0; m < 4; ++m) {
            #pragma unroll
            for (int n = 0; n < 4; ++n) {
                acc[m][n] = __builtin_amdgcn_mfma_f32_16x16x32_bf16(ah[m], bh[n], acc[m][n], 0, 0, 0);
                acc[m][n] = __builtin_amdgcn_mfma_f32_16x16x32_bf16(ah[m], bl[n], acc[m][n], 0, 0, 0);
                acc[m][n] = __builtin_amdgcn_mfma_f32_16x16x32_bf16(al[m], bh[n], acc[m][n], 0, 0, 0);
            }
        }
        __syncthreads();
    }

    // ---- epilogue: store H, fused alpha dots (wave partials -> atomicAdd) ----
    const int gj = lane >> 4;
    float asv[4], adv[4];
    #pragma unroll
    for (int n = 0; n < 4; ++n) {
        int col = wv * 64 + n * 16 + r16;
        asv[n] = a_s[col];
        adv[n] = a_d[col];
    }
    #pragma unroll
    for (int m = 0; m < 4; ++m) {
        #pragma unroll
        for (int j = 0; j < 4; ++j) {
            int row = rowg + m * 16 + gj * 4 + j;
            bool ok = row < N_NODES;
            float ss = 0.f, sd = 0.f;
            #pragma unroll
            for (int n = 0; n < 4; ++n) {
                float v = acc[m][n][j];
                if (ok) H[row * 256 + wv * 64 + n * 16 + r16] = v;
                ss += v * asv[n];
                sd += v * adv[n];
            }
            #pragma unroll
            for (int o = 1; o < 16; o <<= 1) {
                ss += __shfl_xor(ss, o);
                sd += __shfl_xor(sd, o);
            }
            if (ok && r16 == 0) {
                atomicAdd(&As[row], ss);
                atomicAdd(&Ad[row], sd);
            }
        }
    }
}

// ---------------- GEMM 32-out (layer 2), fused alpha dots ----------------

__global__ __launch_bounds__(256) void k_gemm32(
        const float* __restrict__ X, const float* __restrict__ W,  // W: [256][32]
        const float* __restrict__ a_s, const float* __restrict__ a_d,
        float* __restrict__ H, float* __restrict__ As, float* __restrict__ Ad) {
    __shared__ float ws[256][32];
    __shared__ float xs[32][36];   // +4 pad: break 8-way bank conflict
    const int tid = threadIdx.x;
    #pragma unroll
    for (int i = 0; i < 8; ++i) {
        int f = tid + i * 256;
        int r = f >> 3, cc = (f & 7) * 4;
        *(float4*)&ws[r][cc] = *(const float4*)&W[r * 32 + cc];
    }
    const int rl = tid >> 3;
    const int cg = (tid & 7) * 4;
    const int rowg = blockIdx.x * 32;
    const int row = rowg + rl;
    const bool valid = row < N_NODES;
    float4 acc = {};
    __syncthreads();

    for (int k0 = 0; k0 < 256; k0 += 32) {
        {
            int r = tid >> 3, kk = (tid & 7) * 4;
            int gr = rowg + r;
            float4 v = {0, 0, 0, 0};
            if (gr < N_NODES) v = *(const float4*)&X[gr * 256 + k0 + kk];
            *(float4*)&xs[r][kk] = v;
        }
        __syncthreads();
        #pragma unroll
        for (int kk = 0; kk < 32; kk += 4) {
            float4 xv = *(const float4*)&xs[rl][kk];
            fma4(acc, xv.x, *(const float4*)&ws[k0 + kk + 0][cg]);
            fma4(acc, xv.y, *(const float4*)&ws[k0 + kk + 1][cg]);
            fma4(acc, xv.z, *(const float4*)&ws[k0 + kk + 2][cg]);
            fma4(acc, xv.w, *(const float4*)&ws[k0 + kk + 3][cg]);
        }
        __syncthreads();
    }

    float ss = dot4(acc, *(const float4*)&a_s[cg]);
    float sd = dot4(acc, *(const float4*)&a_d[cg]);
    #pragma unroll
    for (int o = 4; o; o >>= 1) {
        ss += __shfl_xor(ss, o);
        sd += __shfl_xor(sd, o);
    }
    if (valid) {
        *(float4*)&H[row * 32 + cg] = acc;
        if ((tid & 7) == 0) { As[row] = ss; Ad[row] = sd; }
    }
}

// ---------------- Aggregation (256-wide), fused bias + swish ----------------

template<bool SWISH>
__global__ __launch_bounds__(256) void k_agg256(
        const float* __restrict__ H, const float* __restrict__ As,
        const float* __restrict__ Ad,
        const int* __restrict__ offs, const int* __restrict__ cnts,
        const int* __restrict__ srcs,
        const float* __restrict__ bias, float* __restrict__ Hout) {
    const int lane = threadIdx.x & 63;
    const int node = blockIdx.x * 4 + (threadIdx.x >> 6);
    if (node >= N_NODES) return;
    const int start = offs[node];
    const int cnt   = cnts[node];
    const float ad  = Ad[node];

    float m = -1e30f;
    for (int base = 0; base < cnt; base += 64) {
        int i = base + lane;
        if (i < cnt) {
            int s = srcs[start + i];
            float e = As[s] + ad;
            e = e > 0.f ? e : NEG_SLOPE * e;
            m = fmaxf(m, e);
        }
    }
    #pragma unroll
    for (int o = 32; o; o >>= 1) m = fmaxf(m, __shfl_xor(m, o));

    float4 acc = {0.f, 0.f, 0.f, 0.f};
    float denom = 0.f;
    const int c0 = lane * 4;
    for (int base = 0; base < cnt; base += 64) {
        int i = base + lane;
        int s = 0; float p = 0.f;
        if (i < cnt) {
            s = srcs[start + i];
            float e = As[s] + ad;
            e = e > 0.f ? e : NEG_SLOPE * e;
            p = __expf(e - m);
            denom += p;
        }
        int lim = min(64, cnt - base);
        for (int j = 0; j < lim; ++j) {
            float pj = __shfl(p, j);
            int   sj = __shfl(s, j);
            const float4 hv = *(const float4*)&H[sj * 256 + c0];
            fma4(acc, pj, hv);
        }
    }
    #pragma unroll
    for (int o = 32; o; o >>= 1) denom += __shfl_xor(denom, o);
    const float inv = 1.f / denom;
    const float4 bv = *(const float4*)&bias[c0];
    float4 o4;
    o4.x = acc.x * inv + bv.x;
    o4.y = acc.y * inv + bv.y;
    o4.z = acc.z * inv + bv.z;
    o4.w = acc.w * inv + bv.w;
    if (SWISH) {
        o4.x = o4.x / (1.f + __expf(-o4.x));
        o4.y = o4.y / (1.f + __expf(-o4.y));
        o4.z = o4.z / (1.f + __expf(-o4.z));
        o4.w = o4.w / (1.f + __expf(-o4.w));
    }
    *(float4*)&Hout[node * 256 + c0] = o4;
}

// ---------------- Final aggregation (32-wide) + bias + log_softmax ----------------

__global__ __launch_bounds__(256) void k_agg_final(
        const float* __restrict__ H,   // [N][32]
        const float* __restrict__ As, const float* __restrict__ Ad,
        const int* __restrict__ offs, const int* __restrict__ cnts,
        const int* __restrict__ srcs,
        const float* __restrict__ bias, float* __restrict__ out) {
    const int lane = threadIdx.x & 63;
    const int node = blockIdx.x * 4 + (threadIdx.x >> 6);
    if (node >= N_NODES) return;
    const int start = offs[node];
    const int cnt   = cnts[node];
    const float ad  = Ad[node];

    float m = -1e30f;
    for (int base = 0; base < cnt; base += 64) {
        int i = base + lane;
        if (i < cnt) {
            int s = srcs[start + i];
            float e = As[s] + ad;
            e = e > 0.f ? e : NEG_SLOPE * e;
            m = fmaxf(m, e);
        }
    }
    #pragma unroll
    for (int o = 32; o; o >>= 1) m = fmaxf(m, __shfl_xor(m, o));

    float acc = 0.f, denom = 0.f;
    const int c = lane & 31;
    for (int base = 0; base < cnt; base += 64) {
        int i = base + lane;
        int s = 0; float p = 0.f;
        if (i < cnt) {
            s = srcs[start + i];
            float e = As[s] + ad;
            e = e > 0.f ? e : NEG_SLOPE * e;
            p = __expf(e - m);
            denom += p;
        }
        int lim = min(64, cnt - base);
        for (int j = 0; j < lim; ++j) {
            float pj = __shfl(p, j);
            int   sj = __shfl(s, j);
            acc += pj * H[sj * 32 + c];
        }
    }
    #pragma unroll
    for (int o = 32; o; o >>= 1) denom += __shfl_xor(denom, o);

    float v = acc / denom + bias[c];
    float mm = v;
    #pragma unroll
    for (int o = 16; o; o >>= 1) mm = fmaxf(mm, __shfl_xor(mm, o));
    float ex = __expf(v - mm), sum = ex;
    #pragma unroll
    for (int o = 16; o; o >>= 1) sum += __shfl_xor(sum, o);
    float r = v - mm - __logf(sum);
    if (lane < 32) out[node * 32 + c] = r;
}

// ---------------- launch ----------------

extern "C" void kernel_launch(void* const* d_in, const int* in_sizes, int n_in,
                              void* d_out, int out_size, void* d_ws, size_t ws_size,
                              hipStream_t stream) {
    const float* x   = (const float*)d_in[0];
    const int*   ei  = (const int*)  d_in[1];
    const float* W0  = (const float*)d_in[2];
    const float* as0 = (const float*)d_in[3];
    const float* ad0 = (const float*)d_in[4];
    const float* b0  = (const float*)d_in[5];
    const float* W1  = (const float*)d_in[6];
    const float* as1 = (const float*)d_in[7];
    const float* ad1 = (const float*)d_in[8];
    const float* b1  = (const float*)d_in[9];
    const float* W2  = (const float*)d_in[10];
    const float* as2 = (const float*)d_in[11];
    const float* ad2 = (const float*)d_in[12];
    const float* b2  = (const float*)d_in[13];
    float* out = (float*)d_out;

    char* ws = (char*)d_ws;
    float* hA    = (float*)(ws + 0);            // 51,200,000 B
    float* hB    = (float*)(ws + 51200000);     // 51,200,000 B
    float* As    = (float*)(ws + 102400000);    // 200,000 B
    float* Ad    = (float*)(ws + 102600000);    // 200,000 B
    int*   cnts  = (int*)  (ws + 102800000);    // 200,000 B
    int*   offs  = (int*)  (ws + 103000000);    // 200,000 B
    int*   cursor= (int*)  (ws + 103200000);    // 200,000 B
    int*   srcs  = (int*)  (ws + 103400000);    // 1,800,000 B
    int*   bsum  = (int*)  (ws + 105200000);    // 1,024 B
    bf16_t* Wth  = (bf16_t*)(ws + 105201024);   // 131,072 B
    bf16_t* Wtl  = (bf16_t*)(ws + 105332096);   // 131,072 B -> end 105,463,168

    const int NB = (N_NODES + 255) / 256;       // 196

    hipMemsetAsync(cnts,   0, N_NODES * sizeof(int), stream);
    hipMemsetAsync(cursor, 0, N_NODES * sizeof(int), stream);

    k_hist   <<<(E_TOT + 255) / 256, 256, 0, stream>>>(ei, cnts);
    k_scan1  <<<NB, 256, 0, stream>>>(cnts, offs, bsum);
    k_scan2  <<<1, 256, 0, stream>>>(bsum, NB);
    k_scan3  <<<NB, 256, 0, stream>>>(offs, bsum);
    k_scatter<<<(E_TOT + 255) / 256, 256, 0, stream>>>(ei, offs, cursor, srcs);

    const int AGG_BLOCKS  = (N_NODES + 3) / 4;    // 12500
    const int GEMM_BLOCKS = (N_NODES + BM - 1) / BM;  // 782

    // layer 0
    k_split_w<<<256, 256, 0, stream>>>(W0, Wth, Wtl);
    hipMemsetAsync(As, 0, 400000, stream);   // As + Ad (contiguous)
    k_gemm256_mfma<<<GEMM_BLOCKS, 256, 0, stream>>>(x, Wth, Wtl, as0, ad0, hA, As, Ad);
    k_agg256<true><<<AGG_BLOCKS, 256, 0, stream>>>(hA, As, Ad, offs, cnts, srcs, b0, hB);
    // layer 1
    k_split_w<<<256, 256, 0, stream>>>(W1, Wth, Wtl);
    hipMemsetAsync(As, 0, 400000, stream);
    k_gemm256_mfma<<<GEMM_BLOCKS, 256, 0, stream>>>(hB, Wth, Wtl, as1, ad1, hA, As, Ad);
    k_agg256<true><<<AGG_BLOCKS, 256, 0, stream>>>(hA, As, Ad, offs, cnts, srcs, b1, hB);
    // layer 2 (+ fused log_softmax)
    k_gemm32<<<(N_NODES + 31) / 32, 256, 0, stream>>>(hB, W2, as2, ad2, hA, As, Ad);
    k_agg_final<<<AGG_BLOCKS, 256, 0, stream>>>(hA, As, Ad, offs, cnts, srcs, b2, out);
}

// Round 3
// 335.392 us; speedup vs baseline: 1.4526x; 1.1368x over previous
//
#include <hip/hip_runtime.h>
#include <math.h>

#define N_NODES 50000
#define E_RAW   400000
#define E_TOT   (E_RAW + N_NODES)   // 450000 incl. self loops
#define NEG_SLOPE 0.2f

typedef __bf16 bf16_t;
typedef bf16_t bf16x8 __attribute__((ext_vector_type(8)));
typedef bf16_t bf16x4 __attribute__((ext_vector_type(4)));
typedef float  f32x4  __attribute__((ext_vector_type(4)));

// LDS bank-group swizzle (applied identically on write and read)
#define SWZ(r) (((r) ^ ((r) >> 3)) & 7)

__device__ __forceinline__ void fma4(float4& a, float s, const float4& w) {
    a.x += s * w.x; a.y += s * w.y; a.z += s * w.z; a.w += s * w.w;
}
__device__ __forceinline__ float dot4(const float4& a, const float4& b) {
    return a.x*b.x + a.y*b.y + a.z*b.z + a.w*b.w;
}

// ---------------- CSR build ----------------

__global__ void k_hist(const int* __restrict__ ei, int* __restrict__ cnt) {
    int e = blockIdx.x * 256 + threadIdx.x;
    if (e >= E_TOT) return;
    int dst = (e < E_RAW) ? ei[E_RAW + e] : (e - E_RAW);
    atomicAdd(&cnt[dst], 1);
}

__global__ void k_scan1(const int* __restrict__ cnt, int* __restrict__ offs,
                        int* __restrict__ bsum) {
    __shared__ int s[256];
    int i = blockIdx.x * 256 + threadIdx.x;
    int v = (i < N_NODES) ? cnt[i] : 0;
    s[threadIdx.x] = v;
    __syncthreads();
    for (int d = 1; d < 256; d <<= 1) {
        int t = (threadIdx.x >= d) ? s[threadIdx.x - d] : 0;
        __syncthreads();
        s[threadIdx.x] += t;
        __syncthreads();
    }
    if (i < N_NODES) offs[i] = s[threadIdx.x] - v;   // exclusive
    if (threadIdx.x == 255) bsum[blockIdx.x] = s[255];
}

__global__ void k_scan2(int* __restrict__ bsum, int nb) {
    __shared__ int s[256];
    int v = (threadIdx.x < nb) ? bsum[threadIdx.x] : 0;
    s[threadIdx.x] = v;
    __syncthreads();
    for (int d = 1; d < 256; d <<= 1) {
        int t = (threadIdx.x >= d) ? s[threadIdx.x - d] : 0;
        __syncthreads();
        s[threadIdx.x] += t;
        __syncthreads();
    }
    if (threadIdx.x < nb) bsum[threadIdx.x] = s[threadIdx.x] - v;  // exclusive
}

__global__ void k_scan3(int* __restrict__ offs, const int* __restrict__ bsum) {
    int i = blockIdx.x * 256 + threadIdx.x;
    if (i < N_NODES) offs[i] += bsum[blockIdx.x];
}

__global__ void k_scatter(const int* __restrict__ ei, const int* __restrict__ offs,
                          int* __restrict__ cursor, int* __restrict__ srcs) {
    int e = blockIdx.x * 256 + threadIdx.x;
    if (e >= E_TOT) return;
    int src, dst;
    if (e < E_RAW) { src = ei[e]; dst = ei[E_RAW + e]; }
    else           { src = dst = e - E_RAW; }
    int pos = offs[dst] + atomicAdd(&cursor[dst], 1);
    srcs[pos] = src;
}

// ---------------- W transpose + bf16 hi/lo split ----------------

__global__ void k_split_w(const float* __restrict__ W,
                          bf16_t* __restrict__ Wth, bf16_t* __restrict__ Wtl) {
    int idx = blockIdx.x * 256 + threadIdx.x;   // 65536 total
    int k = idx >> 8, n = idx & 255;
    float v = W[k * 256 + n];
    bf16_t h = (bf16_t)v;
    Wth[n * 256 + k] = h;
    Wtl[n * 256 + k] = (bf16_t)(v - (float)h);
}

// ---------------- MFMA GEMM, fused alpha dots ----------------
// BM=64 rows/block, BN=256, BK=32. 4 waves; wave w owns cols w*64..+63.
// A fp32 (layer 0): split hi/lo, 3 mfma per fragment. A bf16: 2 mfma.

#define BM 64
#define BK 32

template<bool ABF>
__global__ __launch_bounds__(256) void k_gemm256_mfma(
        const void* __restrict__ Xv,
        const bf16_t* __restrict__ Bth, const bf16_t* __restrict__ Btl,
        const float* __restrict__ a_s, const float* __restrict__ a_d,
        bf16_t* __restrict__ Hb, float* __restrict__ As, float* __restrict__ Ad) {
    __shared__ __align__(16) bf16_t AhS[BM * BK];
    __shared__ __align__(16) bf16_t AlS[BM * BK];
    __shared__ __align__(16) bf16_t BhS[256 * BK];
    __shared__ __align__(16) bf16_t BlS[256 * BK];

    const int tid  = threadIdx.x;
    const int lane = tid & 63;
    const int wv   = tid >> 6;
    const int rowg = blockIdx.x * BM;

    f32x4 acc[4][4] = {};

    const int ar = tid >> 2;
    const int ak = (tid & 3) * 8;
    const int arow_g = min(rowg + ar, N_NODES - 1);
    const int ae = ((ar * BK + ak) ^ (SWZ(ar) << 3));
    const int bbase = tid * BK;
    const int bx = SWZ(tid) << 3;

    const int r16  = lane & 15;
    const int koff = (lane >> 4) * 8;

    for (int k0 = 0; k0 < 256; k0 += BK) {
        // ---- stage A ----
        if (ABF) {
            const bf16_t* Xb = (const bf16_t*)Xv;
            *(bf16x8*)&AhS[ae] = *(const bf16x8*)&Xb[arow_g * 256 + k0 + ak];
        } else {
            const float* X = (const float*)Xv;
            float4 v0 = *(const float4*)&X[arow_g * 256 + k0 + ak];
            float4 v1 = *(const float4*)&X[arow_g * 256 + k0 + ak + 4];
            float xv8[8] = {v0.x, v0.y, v0.z, v0.w, v1.x, v1.y, v1.z, v1.w};
            bf16x8 hi, lo;
            #pragma unroll
            for (int i = 0; i < 8; ++i) {
                bf16_t h = (bf16_t)xv8[i];
                hi[i] = h;
                lo[i] = (bf16_t)(xv8[i] - (float)h);
            }
            *(bf16x8*)&AhS[ae] = hi;
            *(bf16x8*)&AlS[ae] = lo;
        }
        // ---- stage B (pre-split bf16) ----
        const bf16x8* gh = (const bf16x8*)&Bth[tid * 256 + k0];
        const bf16x8* gl = (const bf16x8*)&Btl[tid * 256 + k0];
        #pragma unroll
        for (int j = 0; j < 4; ++j) {
            *(bf16x8*)&BhS[(bbase + j * 8) ^ bx] = gh[j];
            *(bf16x8*)&BlS[(bbase + j * 8) ^ bx] = gl[j];
        }
        __syncthreads();

        bf16x8 ah[4], al[4], bh[4], bl[4];
        #pragma unroll
        for (int m = 0; m < 4; ++m) {
            int row = m * 16 + r16;
            int e = ((row * BK + koff) ^ (SWZ(row) << 3));
            ah[m] = *(const bf16x8*)&AhS[e];
            if (!ABF) al[m] = *(const bf16x8*)&AlS[e];
        }
        #pragma unroll
        for (int n = 0; n < 4; ++n) {
            int col = wv * 64 + n * 16 + r16;
            int e = ((col * BK + koff) ^ (SWZ(col) << 3));
            bh[n] = *(const bf16x8*)&BhS[e];
            bl[n] = *(const bf16x8*)&BlS[e];
        }
        #pragma unroll
        for (int m = 0; m < 4; ++m) {
            #pragma unroll
            for (int n = 0; n < 4; ++n) {
                acc[m][n] = __builtin_amdgcn_mfma_f32_16x16x32_bf16(ah[m], bh[n], acc[m][n], 0, 0, 0);
                acc[m][n] = __builtin_amdgcn_mfma_f32_16x16x32_bf16(ah[m], bl[n], acc[m][n], 0, 0, 0);
                if (!ABF)
                    acc[m][n] = __builtin_amdgcn_mfma_f32_16x16x32_bf16(al[m], bh[n], acc[m][n], 0, 0, 0);
            }
        }
        __syncthreads();
    }

    // ---- epilogue: store bf16 H, fused alpha dots ----
    const int gj = lane >> 4;
    float asv[4], adv[4];
    #pragma unroll
    for (int n = 0; n < 4; ++n) {
        int col = wv * 64 + n * 16 + r16;
        asv[n] = a_s[col];
        adv[n] = a_d[col];
    }
    #pragma unroll
    for (int m = 0; m < 4; ++m) {
        #pragma unroll
        for (int j = 0; j < 4; ++j) {
            int row = rowg + m * 16 + gj * 4 + j;
            bool ok = row < N_NODES;
            float ss = 0.f, sd = 0.f;
            #pragma unroll
            for (int n = 0; n < 4; ++n) {
                float v = acc[m][n][j];
                if (ok) Hb[row * 256 + wv * 64 + n * 16 + r16] = (bf16_t)v;
                ss += v * asv[n];
                sd += v * adv[n];
            }
            #pragma unroll
            for (int o = 1; o < 16; o <<= 1) {
                ss += __shfl_xor(ss, o);
                sd += __shfl_xor(sd, o);
            }
            if (ok && r16 == 0) {
                atomicAdd(&As[row], ss);
                atomicAdd(&Ad[row], sd);
            }
        }
    }
}

// ---------------- GEMM 32-out (layer 2), bf16 input, fused alpha dots ----------------

__global__ __launch_bounds__(256) void k_gemm32(
        const bf16_t* __restrict__ Xb, const float* __restrict__ W,  // W: [256][32]
        const float* __restrict__ a_s, const float* __restrict__ a_d,
        float* __restrict__ H, float* __restrict__ As, float* __restrict__ Ad) {
    __shared__ float ws[256][32];
    __shared__ float xs[32][36];
    const int tid = threadIdx.x;
    #pragma unroll
    for (int i = 0; i < 8; ++i) {
        int f = tid + i * 256;
        int r = f >> 3, cc = (f & 7) * 4;
        *(float4*)&ws[r][cc] = *(const float4*)&W[r * 32 + cc];
    }
    const int rl = tid >> 3;
    const int cg = (tid & 7) * 4;
    const int rowg = blockIdx.x * 32;
    const int row = rowg + rl;
    const bool valid = row < N_NODES;
    float4 acc = {};
    __syncthreads();

    for (int k0 = 0; k0 < 256; k0 += 32) {
        {
            int r = tid >> 3, kk = (tid & 7) * 4;
            int gr = rowg + r;
            float4 v = {0, 0, 0, 0};
            if (gr < N_NODES) {
                bf16x4 bv = *(const bf16x4*)&Xb[gr * 256 + k0 + kk];
                v.x = (float)bv[0]; v.y = (float)bv[1];
                v.z = (float)bv[2]; v.w = (float)bv[3];
            }
            *(float4*)&xs[r][kk] = v;
        }
        __syncthreads();
        #pragma unroll
        for (int kk = 0; kk < 32; kk += 4) {
            float4 xv = *(const float4*)&xs[rl][kk];
            fma4(acc, xv.x, *(const float4*)&ws[k0 + kk + 0][cg]);
            fma4(acc, xv.y, *(const float4*)&ws[k0 + kk + 1][cg]);
            fma4(acc, xv.z, *(const float4*)&ws[k0 + kk + 2][cg]);
            fma4(acc, xv.w, *(const float4*)&ws[k0 + kk + 3][cg]);
        }
        __syncthreads();
    }

    float ss = dot4(acc, *(const float4*)&a_s[cg]);
    float sd = dot4(acc, *(const float4*)&a_d[cg]);
    #pragma unroll
    for (int o = 4; o; o >>= 1) {
        ss += __shfl_xor(ss, o);
        sd += __shfl_xor(sd, o);
    }
    if (valid) {
        *(float4*)&H[row * 32 + cg] = acc;
        if ((tid & 7) == 0) { As[row] = ss; Ad[row] = sd; }
    }
}

// ---------------- Attention: per-edge exp weights + per-node 1/denom ----------------
// 1 wave per dst node, lanes parallel over edges.

__global__ __launch_bounds__(256) void k_attn(
        const float* __restrict__ As, const float* __restrict__ Ad,
        const int* __restrict__ offs, const int* __restrict__ cnts,
        const int* __restrict__ srcs,
        int2* __restrict__ meta, float* __restrict__ inv) {
    const int lane = threadIdx.x & 63;
    int node = blockIdx.x * 4 + (threadIdx.x >> 6);
    if (node >= N_NODES) return;
    node = __builtin_amdgcn_readfirstlane(node);
    const int start = offs[node];
    const int cnt   = cnts[node];
    const float ad  = Ad[node];

    float m = -1e30f;
    for (int base = 0; base < cnt; base += 64) {
        int i = base + lane;
        if (i < cnt) {
            float e = As[srcs[start + i]] + ad;
            e = e > 0.f ? e : NEG_SLOPE * e;
            m = fmaxf(m, e);
        }
    }
    #pragma unroll
    for (int o = 32; o; o >>= 1) m = fmaxf(m, __shfl_xor(m, o));

    float denom = 0.f;
    for (int base = 0; base < cnt; base += 64) {
        int i = base + lane;
        if (i < cnt) {
            int s = srcs[start + i];
            float e = As[s] + ad;
            e = e > 0.f ? e : NEG_SLOPE * e;
            float p = __expf(e - m);
            denom += p;
            meta[start + i] = make_int2(s, __float_as_int(p));
        }
    }
    #pragma unroll
    for (int o = 32; o; o >>= 1) denom += __shfl_xor(denom, o);
    if (lane == 0) inv[node] = 1.f / denom;
}

// ---------------- Gather (256-wide bf16), fused bias + swish ----------------
// 1 wave per node; lane owns cols lane*4..+3; meta loads are wave-uniform (scalar).

__global__ __launch_bounds__(256) void k_gather256(
        const bf16_t* __restrict__ Hb, const int2* __restrict__ meta,
        const int* __restrict__ offs, const int* __restrict__ cnts,
        const float* __restrict__ inv,
        const float* __restrict__ bias, bf16_t* __restrict__ Hout) {
    const int lane = threadIdx.x & 63;
    int node = blockIdx.x * 4 + (threadIdx.x >> 6);
    if (node >= N_NODES) return;
    node = __builtin_amdgcn_readfirstlane(node);
    const int start = offs[node];
    const int cnt   = cnts[node];
    const float iv  = inv[node];
    const int c0 = lane * 4;

    float4 acc = {0.f, 0.f, 0.f, 0.f};
    for (int j = 0; j < cnt; j += 4) {
        int2 mp[4];
        #pragma unroll
        for (int k = 0; k < 4; ++k) mp[k] = meta[start + j + k];  // pad-safe
        #pragma unroll
        for (int k = 0; k < 4; ++k) {
            float p = (j + k < cnt) ? __int_as_float(mp[k].y) : 0.f;
            bf16x4 hv = *(const bf16x4*)&Hb[mp[k].x * 256 + c0];
            acc.x += p * (float)hv[0];
            acc.y += p * (float)hv[1];
            acc.z += p * (float)hv[2];
            acc.w += p * (float)hv[3];
        }
    }

    const float4 bv = *(const float4*)&bias[c0];
    float4 o4;
    o4.x = acc.x * iv + bv.x;
    o4.y = acc.y * iv + bv.y;
    o4.z = acc.z * iv + bv.z;
    o4.w = acc.w * iv + bv.w;
    o4.x = o4.x / (1.f + __expf(-o4.x));
    o4.y = o4.y / (1.f + __expf(-o4.y));
    o4.z = o4.z / (1.f + __expf(-o4.z));
    o4.w = o4.w / (1.f + __expf(-o4.w));
    bf16x4 st = {(bf16_t)o4.x, (bf16_t)o4.y, (bf16_t)o4.z, (bf16_t)o4.w};
    *(bf16x4*)&Hout[node * 256 + c0] = st;
}

// ---------------- Final gather (32-wide fp32) + bias + log_softmax ----------------

__global__ __launch_bounds__(256) void k_gather_final(
        const float* __restrict__ Hc,   // [N][32]
        const int2* __restrict__ meta,
        const int* __restrict__ offs, const int* __restrict__ cnts,
        const float* __restrict__ inv,
        const float* __restrict__ bias, float* __restrict__ out) {
    const int lane = threadIdx.x & 63;
    int node = blockIdx.x * 4 + (threadIdx.x >> 6);
    if (node >= N_NODES) return;
    node = __builtin_amdgcn_readfirstlane(node);
    const int start = offs[node];
    const int cnt   = cnts[node];
    const float iv  = inv[node];
    const int c = lane & 31;

    float acc = 0.f;
    for (int j = 0; j < cnt; j += 4) {
        int2 mp[4];
        #pragma unroll
        for (int k = 0; k < 4; ++k) mp[k] = meta[start + j + k];
        #pragma unroll
        for (int k = 0; k < 4; ++k) {
            float p = (j + k < cnt) ? __int_as_float(mp[k].y) : 0.f;
            acc += p * Hc[mp[k].x * 32 + c];
        }
    }

    float v = acc * iv + bias[c];
    float mm = v;
    #pragma unroll
    for (int o = 16; o; o >>= 1) mm = fmaxf(mm, __shfl_xor(mm, o));
    float ex = __expf(v - mm), sum = ex;
    #pragma unroll
    for (int o = 16; o; o >>= 1) sum += __shfl_xor(sum, o);
    float r = v - mm - __logf(sum);
    if (lane < 32) out[node * 32 + c] = r;
}

// ---------------- launch ----------------

extern "C" void kernel_launch(void* const* d_in, const int* in_sizes, int n_in,
                              void* d_out, int out_size, void* d_ws, size_t ws_size,
                              hipStream_t stream) {
    const float* x   = (const float*)d_in[0];
    const int*   ei  = (const int*)  d_in[1];
    const float* W0  = (const float*)d_in[2];
    const float* as0 = (const float*)d_in[3];
    const float* ad0 = (const float*)d_in[4];
    const float* b0  = (const float*)d_in[5];
    const float* W1  = (const float*)d_in[6];
    const float* as1 = (const float*)d_in[7];
    const float* ad1 = (const float*)d_in[8];
    const float* b1  = (const float*)d_in[9];
    const float* W2  = (const float*)d_in[10];
    const float* as2 = (const float*)d_in[11];
    const float* ad2 = (const float*)d_in[12];
    const float* b2  = (const float*)d_in[13];
    float* out = (float*)d_out;

    char* ws = (char*)d_ws;
    bf16_t* hA_b  = (bf16_t*)(ws + 0);           // 25,600,000
    bf16_t* hB_b  = (bf16_t*)(ws + 25600000);    // 25,600,000
    float*  hC    = (float*) (ws + 51200000);    //  6,400,000
    float*  As    = (float*) (ws + 57600000);    //    200,000
    float*  Ad    = (float*) (ws + 57800000);    //    200,000
    float*  inv   = (float*) (ws + 58000000);    //    200,000
    int*    cnts  = (int*)   (ws + 58200000);    //    200,000
    int*    offs  = (int*)   (ws + 58400000);    //    200,000
    int*    cursor= (int*)   (ws + 58600000);    //    200,000
    int*    srcs  = (int*)   (ws + 58800000);    //  1,800,000
    int2*   meta  = (int2*)  (ws + 60600000);    //  3,600,032 (E_TOT+4)
    int*    bsum  = (int*)   (ws + 64200032);    //      1,024
    bf16_t* Wth   = (bf16_t*)(ws + 64201056);    //    131,072
    bf16_t* Wtl   = (bf16_t*)(ws + 64332128);    //    131,072

    const int NB = (N_NODES + 255) / 256;       // 196

    hipMemsetAsync(cnts,   0, N_NODES * sizeof(int), stream);
    hipMemsetAsync(cursor, 0, N_NODES * sizeof(int), stream);
    hipMemsetAsync((char*)meta + (size_t)E_TOT * 8, 0, 32, stream);  // pad

    k_hist   <<<(E_TOT + 255) / 256, 256, 0, stream>>>(ei, cnts);
    k_scan1  <<<NB, 256, 0, stream>>>(cnts, offs, bsum);
    k_scan2  <<<1, 256, 0, stream>>>(bsum, NB);
    k_scan3  <<<NB, 256, 0, stream>>>(offs, bsum);
    k_scatter<<<(E_TOT + 255) / 256, 256, 0, stream>>>(ei, offs, cursor, srcs);

    const int AGG_BLOCKS  = (N_NODES + 3) / 4;        // 12500
    const int GEMM_BLOCKS = (N_NODES + BM - 1) / BM;  // 782

    // layer 0 (fp32 A)
    k_split_w<<<256, 256, 0, stream>>>(W0, Wth, Wtl);
    hipMemsetAsync(As, 0, 400000, stream);   // As + Ad contiguous
    k_gemm256_mfma<false><<<GEMM_BLOCKS, 256, 0, stream>>>(x, Wth, Wtl, as0, ad0, hA_b, As, Ad);
    k_attn<<<AGG_BLOCKS, 256, 0, stream>>>(As, Ad, offs, cnts, srcs, meta, inv);
    k_gather256<<<AGG_BLOCKS, 256, 0, stream>>>(hA_b, meta, offs, cnts, inv, b0, hB_b);
    // layer 1 (bf16 A)
    k_split_w<<<256, 256, 0, stream>>>(W1, Wth, Wtl);
    hipMemsetAsync(As, 0, 400000, stream);
    k_gemm256_mfma<true><<<GEMM_BLOCKS, 256, 0, stream>>>(hB_b, Wth, Wtl, as1, ad1, hA_b, As, Ad);
    k_attn<<<AGG_BLOCKS, 256, 0, stream>>>(As, Ad, offs, cnts, srcs, meta, inv);
    k_gather256<<<AGG_BLOCKS, 256, 0, stream>>>(hA_b, meta, offs, cnts, inv, b1, hB_b);
    // layer 2 (+ fused log_softmax)
    k_gemm32<<<(N_NODES + 31) / 32, 256, 0, stream>>>(hB_b, W2, as2, ad2, hC, As, Ad);
    k_attn<<<AGG_BLOCKS, 256, 0, stream>>>(As, Ad, offs, cnts, srcs, meta, inv);
    k_gather_final<<<AGG_BLOCKS, 256, 0, stream>>>(hC, meta, offs, cnts, inv, b2, out);
}